// Round 3
// baseline (1185.610 us; speedup 1.0000x reference)
//
#include <hip/hip_runtime.h>
#include <hip/hip_fp16.h>
#include <math.h>

#define TEMPERATURE 0.07f

// ---------------- ws layout (float offsets) ----------------
#define WS_COST   0          // 128*128*128 = 2097152
#define WS_SIM    2097152    // 16384
#define WS_IVG    2113536    // 128
#define WS_ITG    2113664    // 128
#define WS_IVV    2113792    // 16384
#define WS_IVT    2130176    // 16384
#define WS_COLS   2146560    // 16384 ints
#define WS_ACC    2162944    // 16 floats

// ---------------- init: zero accumulators ----------------
__global__ void k_init(float* acc) {
    if (threadIdx.x < 16) acc[threadIdx.x] = 0.0f;
}

// ---------------- row inverse norms: x [rows][1024] ----------------
__global__ __launch_bounds__(256) void k_invnorm(const float* __restrict__ x,
                                                 float* __restrict__ out, int rows) {
    int wid = threadIdx.x >> 6;
    int lane = threadIdx.x & 63;
    int row = blockIdx.x * 4 + wid;
    if (row >= rows) return;
    const float* xr = x + (size_t)row * 1024;
    float s = 0.0f;
#pragma unroll
    for (int i = 0; i < 4; i++) {
        float4 v = *(const float4*)&xr[i * 256 + lane * 4];
        s += v.x * v.x + v.y * v.y + v.z * v.z + v.w * v.w;
    }
#pragma unroll
    for (int off = 32; off > 0; off >>= 1) s += __shfl_xor(s, off);
    if (lane == 0) out[row] = 1.0f / fmaxf(sqrtf(s), 1e-12f);
}

// ---------------- sim[i][j] = dot(v_g[i], t_g[j]) * iv[i]*it[j] / TEMP ----------------
__global__ __launch_bounds__(128) void k_sim(const float* __restrict__ vg,
                                             const float* __restrict__ tg,
                                             const float* __restrict__ ivg,
                                             const float* __restrict__ itg,
                                             float* __restrict__ sim) {
    int i = blockIdx.x, j = threadIdx.x;
    const float* vr = vg + (size_t)i * 1024;
    const float* tr = tg + (size_t)j * 1024;
    float acc = 0.0f;
    for (int k = 0; k < 1024; k += 4) {
        float4 a = *(const float4*)&vr[k];
        float4 b = *(const float4*)&tr[k];
        acc += a.x * b.x + a.y * b.y + a.z * b.z + a.w * b.w;
    }
    sim[i * 128 + j] = acc * ivg[i] * itg[j] / TEMPERATURE;
}

// ---------------- L_global from sim (single block, 128 threads) ----------------
__global__ __launch_bounds__(128) void k_global(const float* __restrict__ sim,
                                                float* __restrict__ acc) {
    __shared__ float red[128];
    int t = threadIdx.x;
    float m = -3e38f, m2 = -3e38f;
    for (int j = 0; j < 128; j++) {
        m = fmaxf(m, sim[t * 128 + j]);
        m2 = fmaxf(m2, sim[j * 128 + t]);
    }
    float s = 0.0f, s2 = 0.0f;
    for (int j = 0; j < 128; j++) {
        s += expf(sim[t * 128 + j] - m);
        s2 += expf(sim[j * 128 + t] - m2);
    }
    float contrib = 2.0f * sim[t * 128 + t] - (m + logf(s)) - (m2 + logf(s2));
    red[t] = contrib;
    __syncthreads();
    for (int o = 64; o > 0; o >>= 1) {
        if (t < o) red[t] += red[t + o];
        __syncthreads();
    }
    if (t == 0) acc[0] = -red[0] / 256.0f;   // 0.5*(mean+mean), negated
}

// ---------------- cost[b][n][m] = 1 - cos(V[b,n], T[b,m]) ----------------
__global__ __launch_bounds__(256) void k_cost(const float* __restrict__ V,
                                              const float* __restrict__ T,
                                              const float* __restrict__ ivv,
                                              const float* __restrict__ ivt,
                                              float* __restrict__ cost) {
    __shared__ float As[16][68];
    __shared__ float Bs[16][68];
    int b = blockIdx.x >> 2;
    int tile = blockIdx.x & 3;
    int n0 = (tile >> 1) * 64, m0 = (tile & 1) * 64;
    int t = threadIdx.x;
    int lr = t >> 2;
    int lq = t & 3;
    int tm = t >> 4;
    int tn = t & 15;
    const float* Vb = V + (size_t)b * 128 * 1024;
    const float* Tb = T + (size_t)b * 128 * 1024;
    float acc[4][4];
#pragma unroll
    for (int i = 0; i < 4; i++)
#pragma unroll
        for (int j = 0; j < 4; j++) acc[i][j] = 0.0f;

    for (int k0 = 0; k0 < 1024; k0 += 16) {
        float4 av = *(const float4*)&Vb[(size_t)(n0 + lr) * 1024 + k0 + lq * 4];
        float4 bv = *(const float4*)&Tb[(size_t)(m0 + lr) * 1024 + k0 + lq * 4];
        __syncthreads();
        As[lq * 4 + 0][lr] = av.x; As[lq * 4 + 1][lr] = av.y;
        As[lq * 4 + 2][lr] = av.z; As[lq * 4 + 3][lr] = av.w;
        Bs[lq * 4 + 0][lr] = bv.x; Bs[lq * 4 + 1][lr] = bv.y;
        Bs[lq * 4 + 2][lr] = bv.z; Bs[lq * 4 + 3][lr] = bv.w;
        __syncthreads();
#pragma unroll
        for (int k = 0; k < 16; k++) {
            float4 a = *(const float4*)&As[k][tm * 4];
            float4 q = *(const float4*)&Bs[k][tn * 4];
            acc[0][0] += a.x * q.x; acc[0][1] += a.x * q.y; acc[0][2] += a.x * q.z; acc[0][3] += a.x * q.w;
            acc[1][0] += a.y * q.x; acc[1][1] += a.y * q.y; acc[1][2] += a.y * q.z; acc[1][3] += a.y * q.w;
            acc[2][0] += a.z * q.x; acc[2][1] += a.z * q.y; acc[2][2] += a.z * q.z; acc[2][3] += a.z * q.w;
            acc[3][0] += a.w * q.x; acc[3][1] += a.w * q.y; acc[3][2] += a.w * q.z; acc[3][3] += a.w * q.w;
        }
    }
    int nb = n0 + tm * 4, mb = m0 + tn * 4;
    float im[4];
#pragma unroll
    for (int j = 0; j < 4; j++) im[j] = ivt[b * 128 + mb + j];
#pragma unroll
    for (int i = 0; i < 4; i++) {
        float in_ = ivv[b * 128 + nb + i];
        float4 o;
        o.x = 1.0f - acc[i][0] * in_ * im[0];
        o.y = 1.0f - acc[i][1] * in_ * im[1];
        o.z = 1.0f - acc[i][2] * in_ * im[2];
        o.w = 1.0f - acc[i][3] * in_ * im[3];
        *(float4*)&cost[((size_t)b * 128 + nb + i) * 128 + mb] = o;
    }
}

// ================= Hungarian (JV), 2 problems interleaved per wave =============
#define HUNG_INF 3.0e38f

__device__ __forceinline__ int rdlane_i(int v, int l) {
    return __builtin_amdgcn_readlane(v, l);
}
__device__ __forceinline__ float rdlane_f(float v, int l) {
    return __int_as_float(__builtin_amdgcn_readlane(__float_as_int(v), l));
}

// full-wave u32 min via DPP (identity UINT_MAX); result valid in lane 63
__device__ __forceinline__ unsigned int dpp_umin_wave(unsigned int x) {
    int o;
    o = __builtin_amdgcn_update_dpp(-1, (int)x, 0x111, 0xF, 0xF, false); // row_shr:1
    x = (x < (unsigned int)o) ? x : (unsigned int)o;
    o = __builtin_amdgcn_update_dpp(-1, (int)x, 0x112, 0xF, 0xF, false); // row_shr:2
    x = (x < (unsigned int)o) ? x : (unsigned int)o;
    o = __builtin_amdgcn_update_dpp(-1, (int)x, 0x114, 0xF, 0xF, false); // row_shr:4
    x = (x < (unsigned int)o) ? x : (unsigned int)o;
    o = __builtin_amdgcn_update_dpp(-1, (int)x, 0x118, 0xF, 0xF, false); // row_shr:8
    x = (x < (unsigned int)o) ? x : (unsigned int)o;
    o = __builtin_amdgcn_update_dpp(-1, (int)x, 0x142, 0xF, 0xF, false); // row_bcast:15
    x = (x < (unsigned int)o) ? x : (unsigned int)o;
    o = __builtin_amdgcn_update_dpp(-1, (int)x, 0x143, 0xF, 0xF, false); // row_bcast:31
    x = (x < (unsigned int)o) ? x : (unsigned int)o;
    return x;
}

__device__ __forceinline__ unsigned int pack_h2(float a, float b) {
    unsigned int ua = (unsigned int)__half_as_ushort(__float2half(a));
    unsigned int ub = (unsigned int)__half_as_ushort(__float2half(b));
    return ua | (ub << 16);
}
__device__ __forceinline__ float h2_lo(unsigned int u) {
    return __half2float(__ushort_as_half((unsigned short)(u & 0xFFFFu)));
}
__device__ __forceinline__ float h2_hi(unsigned int u) {
    return __half2float(__ushort_as_half((unsigned short)(u >> 16)));
}

struct JV {
    float v0, v1, u0, u1;      // duals (lane-owned: cols/rows lane, lane+64)
    float minv0, minv1;
    int way0, way1;
    int p0, p1;                // row matched to col lane / lane+64 (-1 none)
    bool used0, used1, intree0, intree1;
    int row;                   // uniform: current outer row
    int i0;                    // uniform: row to expand this tick
    int j0;                    // uniform: column whose matched row is expanding (128=root)
    int cnt;                   // uniform guard
    bool done;
};

__device__ __forceinline__ void jv_newrow(JV& s, int lane) {
    s.minv0 = s.minv1 = HUNG_INF;
    s.way0 = s.way1 = 128;
    s.used0 = s.used1 = false;
    s.intree0 = (s.row < 64) && (lane == s.row);
    s.intree1 = (s.row >= 64) && (lane == s.row - 64);
    s.j0 = 128;
    s.i0 = s.row;
    s.cnt = 0;
}

__device__ __forceinline__ void jv_init(JV& s, int lane) {
    s.v0 = s.v1 = s.u0 = s.u1 = 0.0f;
    s.p0 = s.p1 = -1;
    s.row = 0;
    s.done = false;
    jv_newrow(s, lane);
}

// one inner-Dijkstra step; `packed` = half2 cost word for row s.i0 at this lane
__device__ __forceinline__ void jv_step(JV& s, unsigned int packed, int lane) {
    float c0 = h2_lo(packed);
    float c1 = h2_hi(packed);
    float ui0 = rdlane_f(s.i0 >= 64 ? s.u1 : s.u0, s.i0 & 63);
    float cur0 = c0 - ui0 - s.v0;
    float cur1 = c1 - ui0 - s.v1;
    if (!s.used0 && cur0 < s.minv0) { s.minv0 = cur0; s.way0 = s.j0; }
    if (!s.used1 && cur1 < s.minv1) { s.minv1 = cur1; s.way1 = s.j0; }
    float cand0 = s.used0 ? HUNG_INF : s.minv0;
    float cand1 = s.used1 ? HUNG_INF : s.minv1;
    // sortable key: biased value bits (top 25) | column index (low 7).
    // cand >= -tiny, so cand+1 > 0 -> IEEE bits monotonic as u32.
    unsigned int k0 = (__float_as_uint(cand0 + 1.0f) & 0xFFFFFF80u) | (unsigned int)lane;
    unsigned int k1 = (__float_as_uint(cand1 + 1.0f) & 0xFFFFFF80u) | (unsigned int)(lane + 64);
    unsigned int k = (k0 < k1) ? k0 : k1;
    k = dpp_umin_wave(k);
    unsigned int kmin = (unsigned int)rdlane_i((int)k, 63);
    int j1 = (int)(kmin & 127u);
    float delta = __uint_as_float(kmin & 0xFFFFFF80u) - 1.0f;   // <= exact min, err < 4e-5
    if (s.used0) s.v0 -= delta; else s.minv0 -= delta;
    if (s.used1) s.v1 -= delta; else s.minv1 -= delta;
    if (s.intree0) s.u0 += delta;
    if (s.intree1) s.u1 += delta;
    int pj = rdlane_i(j1 >= 64 ? s.p1 : s.p0, j1 & 63);
    if (pj >= 0 && ++s.cnt <= 200) {
        // column j1 joins tree; its matched row pj expands next
        if (lane == (j1 & 63)) { if (j1 >= 64) s.used1 = true; else s.used0 = true; }
        if (lane == (pj & 63)) { if (pj < 64) s.intree0 = true; else s.intree1 = true; }
        s.j0 = j1;
        s.i0 = pj;
    } else {
        // augment along alternating path from j1
        int j = j1;
        while (j != 128) {
            int w = rdlane_i(j >= 64 ? s.way1 : s.way0, j & 63);
            int pw = (w == 128) ? s.row : rdlane_i(w >= 64 ? s.p1 : s.p0, w & 63);
            if (lane == (j & 63)) { if (j >= 64) s.p1 = pw; else s.p0 = pw; }
            j = w;
        }
        s.row++;
        if (s.row < 128) jv_newrow(s, lane);
        else s.done = true;
    }
}

// one wave solves TWO batch problems, interleaved to overlap LDS latency.
__global__ __launch_bounds__(64) void k_hungarian(const float* __restrict__ cost,
                                                  int* __restrict__ cols) {
    __shared__ unsigned int PA[128 * 64];   // 32 KB: half2(C[i][l], C[i][l+64])
    __shared__ unsigned int PB[128 * 64];   // 32 KB
    int pr = blockIdx.x;                    // pair index 0..63
    int bA = pr * 2, bB = pr * 2 + 1;
    int lane = threadIdx.x;
    const float* CA = cost + (size_t)bA * 16384;
    const float* CB = cost + (size_t)bB * 16384;
    for (int r = 0; r < 128; ++r) {
        PA[r * 64 + lane] = pack_h2(CA[r * 128 + lane], CA[r * 128 + 64 + lane]);
        PB[r * 64 + lane] = pack_h2(CB[r * 128 + lane], CB[r * 128 + 64 + lane]);
    }
    __syncthreads();

    JV A, B;
    jv_init(A, lane);
    jv_init(B, lane);
    while (!(A.done && B.done)) {
        // issue BOTH problems' row reads first so B's latency hides under A's compute
        unsigned int pka = PA[A.i0 * 64 + lane];
        unsigned int pkb = PB[B.i0 * 64 + lane];
        if (!A.done) jv_step(A, pka, lane);
        if (!B.done) jv_step(B, pkb, lane);
    }
    if (A.p0 >= 0) cols[bA * 128 + A.p0] = lane;
    if (A.p1 >= 0) cols[bA * 128 + A.p1] = lane + 64;
    if (B.p0 >= 0) cols[bB * 128 + B.p0] = lane;
    if (B.p1 >= 0) cols[bB * 128 + B.p1] = lane + 64;
}

// ---------------- node MSE: one block per (b,n) row ----------------
__global__ __launch_bounds__(256) void k_node(const float* __restrict__ V,
                                              const float* __restrict__ T,
                                              const int* __restrict__ cols,
                                              float* __restrict__ acc) {
    int bn = blockIdx.x;
    int b = bn >> 7, n = bn & 127;
    int c = cols[bn];
    const float* vr = V + ((size_t)b * 128 + n) * 1024;
    const float* tr = T + ((size_t)b * 128 + c) * 1024;
    int t = threadIdx.x;
    float4 a = *(const float4*)&vr[t * 4];
    float4 bb = *(const float4*)&tr[t * 4];
    float dx = a.x - bb.x, dy = a.y - bb.y, dz = a.z - bb.z, dw = a.w - bb.w;
    float s = dx * dx + dy * dy + dz * dz + dw * dw;
#pragma unroll
    for (int off = 32; off > 0; off >>= 1) s += __shfl_xor(s, off);
    __shared__ float wsum[4];
    if ((t & 63) == 0) wsum[t >> 6] = s;
    __syncthreads();
    if (t == 0) atomicAdd(&acc[1], wsum[0] + wsum[1] + wsum[2] + wsum[3]);
}

// ---------------- graph MSE ----------------
__global__ __launch_bounds__(256) void k_graph(const float* __restrict__ Av,
                                               const float* __restrict__ At,
                                               float* __restrict__ acc) {
    size_t idx = ((size_t)blockIdx.x * 256 + threadIdx.x) * 4;
    float4 a = *(const float4*)&Av[idx];
    float4 bb = *(const float4*)&At[idx];
    float dx = a.x - bb.x, dy = a.y - bb.y, dz = a.z - bb.z, dw = a.w - bb.w;
    float s = dx * dx + dy * dy + dz * dz + dw * dw;
#pragma unroll
    for (int off = 32; off > 0; off >>= 1) s += __shfl_xor(s, off);
    __shared__ float wsum[4];
    int t = threadIdx.x;
    if ((t & 63) == 0) wsum[t >> 6] = s;
    __syncthreads();
    if (t == 0) atomicAdd(&acc[2], wsum[0] + wsum[1] + wsum[2] + wsum[3]);
}

// ---------------- finalize ----------------
__global__ void k_final(const float* __restrict__ acc, float* __restrict__ out) {
    float lg = acc[0];
    float ln = acc[1] / 16777216.0f;   // 128*128*1024
    float lgr = acc[2] / 2097152.0f;   // 128*128*128
    out[0] = lg + ln + lgr;
    out[1] = lg;
    out[2] = ln;
    out[3] = lgr;
}

extern "C" void kernel_launch(void* const* d_in, const int* in_sizes, int n_in,
                              void* d_out, int out_size, void* d_ws, size_t ws_size,
                              hipStream_t stream) {
    const float* vg = (const float*)d_in[0];
    const float* tg = (const float*)d_in[1];
    const float* V  = (const float*)d_in[2];
    const float* T  = (const float*)d_in[3];
    const float* Av = (const float*)d_in[4];
    const float* At = (const float*)d_in[5];
    float* out = (float*)d_out;
    float* ws = (float*)d_ws;

    float* cost = ws + WS_COST;
    float* sim  = ws + WS_SIM;
    float* ivg  = ws + WS_IVG;
    float* itg  = ws + WS_ITG;
    float* ivv  = ws + WS_IVV;
    float* ivt  = ws + WS_IVT;
    int*   cols = (int*)(ws + WS_COLS);
    float* acc  = ws + WS_ACC;

    k_init<<<1, 16, 0, stream>>>(acc);

    k_invnorm<<<32, 256, 0, stream>>>(vg, ivg, 128);
    k_invnorm<<<32, 256, 0, stream>>>(tg, itg, 128);
    k_invnorm<<<4096, 256, 0, stream>>>(V, ivv, 16384);
    k_invnorm<<<4096, 256, 0, stream>>>(T, ivt, 16384);

    k_sim<<<128, 128, 0, stream>>>(vg, tg, ivg, itg, sim);
    k_global<<<1, 128, 0, stream>>>(sim, acc);

    k_cost<<<512, 256, 0, stream>>>(V, T, ivv, ivt, cost);
    k_hungarian<<<64, 64, 0, stream>>>(cost, cols);

    k_node<<<16384, 256, 0, stream>>>(V, T, cols, acc);
    k_graph<<<2048, 256, 0, stream>>>(Av, At, acc);

    k_final<<<1, 1, 0, stream>>>(acc, out);
}